// Round 3
// baseline (174.953 us; speedup 1.0000x reference)
//
#include <hip/hip_runtime.h>

// YOLO loss, fp32. predictions: (batch,7,7,13), target: (batch,7,7,8), out: scalar.
// R2 post-mortem: LDS double-buffer + __syncthreads = phase-locked burst/stall,
// 2.7 TB/s effective. R3: 4 cells = 52 floats = exactly 13 float4 -> each thread
// owns 4 cells, loads them as 13 aligned float4 + 8 target float4, NO LDS, NO
// barriers in the hot path. 21 independent vmem ops/thread keep queues full.

static constexpr int PRED_C = 13;   // 5*B + C
static constexpr int TGT_C  = 8;    // 1 + 4 + 3
static constexpr float L_NOOBJ = 0.5f;
static constexpr float L_COORD = 5.0f;
static constexpr float EPSI = 1e-6f;

__device__ __forceinline__ float iou_f(float ax, float ay, float aw, float ah,
                                       float bx, float by, float bw, float bh) {
    float ax1 = ax - aw * 0.5f, ax2 = ax + aw * 0.5f;
    float ay1 = ay - ah * 0.5f, ay2 = ay + ah * 0.5f;
    float bx1 = bx - bw * 0.5f, bx2 = bx + bw * 0.5f;
    float by1 = by - bh * 0.5f, by2 = by + bh * 0.5f;
    float iw = fmaxf(fminf(ax2, bx2) - fmaxf(ax1, bx1), 0.0f);
    float ih = fmaxf(fminf(ay2, by2) - fmaxf(ay1, by1), 0.0f);
    float inter = iw * ih;
    float uni = (ax2 - ax1) * (ay2 - ay1) + (bx2 - bx1) * (by2 - by1) - inter;
    return inter / (uni + EPSI);
}

__device__ __forceinline__ float cell_loss(const float* __restrict__ p,
                                           const float* __restrict__ tg) {
    float m  = (tg[0] == 1.0f) ? 1.0f : 0.0f;
    float tx = tg[1], ty = tg[2], tw = tg[3], th = tg[4];

    float b1c = p[0],  b1x = p[1],  b1y = p[2],  b1w = p[3], b1h = p[4];
    float b2c = p[5],  b2x = p[6],  b2y = p[7],  b2w = p[8], b2h = p[9];

    float i1 = iou_f(b1x, b1y, b1w, b1h, tx, ty, tw, th);
    float i2 = iou_f(b2x, b2y, b2w, b2h, tx, ty, tw, th);
    bool pick1 = i1 > i2;
    float iou = pick1 ? i1 : i2;
    float sc  = pick1 ? b1c : b2c;
    float sx  = pick1 ? b1x : b2x;
    float sy  = pick1 ? b1y : b2y;
    float sw  = pick1 ? b1w : b2w;
    float sh  = pick1 ? b1h : b2h;
    float uc  = pick1 ? b2c : b1c;

    float dx = sx - tx, dy = sy - ty;
    // sign(w)*sqrt(|w|): copysign matches jnp.sign semantics for finite inputs.
    float dw = copysignf(sqrtf(fabsf(sw)), sw) - sqrtf(tw);
    float dh = copysignf(sqrtf(fabsf(sh)), sh) - sqrtf(th);
    float l_coord = dx * dx + dy * dy + dw * dw + dh * dh;

    float doj = sc - iou;
    float d0 = p[10] - tg[5], d1 = p[11] - tg[6], d2 = p[12] - tg[7];
    float l_cls = d0 * d0 + d1 * d1 + d2 * d2;
    float l_noobj = m * uc * uc + (1.0f - m) * (b1c * b1c + b2c * b2c);

    return m * (L_COORD * l_coord + doj * doj + l_cls) + L_NOOBJ * l_noobj;
}

__global__ __launch_bounds__(256) void yolo_main(const float* __restrict__ pred,
                                                 const float* __restrict__ tgt,
                                                 float* __restrict__ partial,
                                                 long long ncells) {
    __shared__ float wsum[4];
    const int t = threadIdx.x;
    const long long tid = (long long)blockIdx.x * 256 + t;
    const long long c0 = tid * 4;

    float acc = 0.0f;
    if (c0 + 4 <= ncells) {
        // 4 cells of predictions = 52 floats = exactly 13 float4, 16B-aligned.
        const float4* p4 = (const float4*)pred + tid * 13;
        float4 P[13];
#pragma unroll
        for (int i = 0; i < 13; ++i) P[i] = p4[i];
        // 4 cells of target = 32 floats = 8 float4.
        const float4* t4 = (const float4*)tgt + tid * 8;
        float4 T[8];
#pragma unroll
        for (int i = 0; i < 8; ++i) T[i] = t4[i];

        const float* pf = (const float*)P;
        const float* tf = (const float*)T;
#pragma unroll
        for (int c = 0; c < 4; ++c)
            acc += cell_loss(pf + c * PRED_C, tf + c * TGT_C);
    } else {
        // generic tail (not hit at the bench shape: ncells % 4 == 0 exact grid)
        for (int c = 0; c < 4; ++c) {
            long long cell = c0 + c;
            if (cell < ncells) {
                float pb[PRED_C], tb[TGT_C];
                for (int i = 0; i < PRED_C; ++i) pb[i] = pred[cell * PRED_C + i];
                for (int i = 0; i < TGT_C; ++i)  tb[i] = tgt[cell * TGT_C + i];
                acc += cell_loss(pb, tb);
            }
        }
    }

    // wave64 shuffle reduction -> one partial per block (deterministic)
#pragma unroll
    for (int off = 32; off > 0; off >>= 1)
        acc += __shfl_down(acc, off, 64);
    if ((t & 63) == 0) wsum[t >> 6] = acc;
    __syncthreads();
    if (t == 0) partial[blockIdx.x] = (wsum[0] + wsum[1]) + (wsum[2] + wsum[3]);
}

__global__ __launch_bounds__(256) void yolo_reduce(const float* __restrict__ partial,
                                                   float* __restrict__ out,
                                                   int nblocks, float inv_batch) {
    __shared__ float wsum[4];
    int t = threadIdx.x;
    float v = 0.0f;
    for (int i = t; i < nblocks; i += 256) v += partial[i];
#pragma unroll
    for (int off = 32; off > 0; off >>= 1)
        v += __shfl_down(v, off, 64);
    if ((t & 63) == 0) wsum[t >> 6] = v;
    __syncthreads();
    if (t == 0) out[0] = ((wsum[0] + wsum[1]) + (wsum[2] + wsum[3])) * inv_batch;
}

extern "C" void kernel_launch(void* const* d_in, const int* in_sizes, int n_in,
                              void* d_out, int out_size, void* d_ws, size_t ws_size,
                              hipStream_t stream) {
    const float* pred = (const float*)d_in[0];
    const float* tgt  = (const float*)d_in[1];
    float* out = (float*)d_out;
    float* partial = (float*)d_ws;

    long long ncells = (long long)in_sizes[1] / TGT_C;   // batch*S*S = 1,605,632
    long long batch  = ncells / 49;                      // S=7
    float inv_batch  = 1.0f / (float)batch;

    long long nthreads = (ncells + 3) / 4;               // 401,408
    int nblocks = (int)((nthreads + 255) / 256);         // 1568

    yolo_main<<<nblocks, 256, 0, stream>>>(pred, tgt, partial, ncells);
    yolo_reduce<<<1, 256, 0, stream>>>(partial, out, nblocks, inv_batch);
}

// Round 4
// 161.522 us; speedup vs baseline: 1.0832x; 1.0832x over previous
//
#include <hip/hip_runtime.h>

// YOLO loss, fp32. predictions: (batch,7,7,13), target: (batch,7,7,8), out: scalar.
// R3 post-mortem: per-thread contiguous float4 loads = lane-stride 208B = 64
// lines/instruction -> request-rate limited at 2 TB/s. R4: back to coalesced
// global_load_lds staging (lane-stride 16B), but the staging unit is the WAVE,
// not the block: private 3328B LDS slab per wave, per-wave vmcnt wait, zero
// __syncthreads in the hot loop -> 32 independent wave pipelines per CU.

static constexpr int PRED_C = 13;   // 5*B + C
static constexpr int TGT_C  = 8;    // 1 + 4 + 3
static constexpr float L_NOOBJ = 0.5f;
static constexpr float L_COORD = 5.0f;
static constexpr float EPSI = 1e-6f;

static constexpr int NBLOCKS = 2048;      // 8 blocks/CU target
static constexpr int WTILE   = 64;        // cells per wave-tile (1 cell/lane)
static constexpr int WTILE_F = WTILE * PRED_C;   // 832 floats = 3328 B

typedef const __attribute__((address_space(1))) unsigned int* gp1_t;
typedef __attribute__((address_space(3))) unsigned int*       lp3_t;

__device__ __forceinline__ float iou_f(float ax, float ay, float aw, float ah,
                                       float bx, float by, float bw, float bh) {
    float ax1 = ax - aw * 0.5f, ax2 = ax + aw * 0.5f;
    float ay1 = ay - ah * 0.5f, ay2 = ay + ah * 0.5f;
    float bx1 = bx - bw * 0.5f, bx2 = bx + bw * 0.5f;
    float by1 = by - bh * 0.5f, by2 = by + bh * 0.5f;
    float iw = fmaxf(fminf(ax2, bx2) - fmaxf(ax1, bx1), 0.0f);
    float ih = fmaxf(fminf(ay2, by2) - fmaxf(ay1, by1), 0.0f);
    float inter = iw * ih;
    float uni = (ax2 - ax1) * (ay2 - ay1) + (bx2 - bx1) * (by2 - by1) - inter;
    return inter / (uni + EPSI);
}

__device__ __forceinline__ float cell_loss(const float* __restrict__ p,
                                           const float* __restrict__ tg) {
    float m  = (tg[0] == 1.0f) ? 1.0f : 0.0f;
    float tx = tg[1], ty = tg[2], tw = tg[3], th = tg[4];

    float b1c = p[0],  b1x = p[1],  b1y = p[2],  b1w = p[3], b1h = p[4];
    float b2c = p[5],  b2x = p[6],  b2y = p[7],  b2w = p[8], b2h = p[9];

    float i1 = iou_f(b1x, b1y, b1w, b1h, tx, ty, tw, th);
    float i2 = iou_f(b2x, b2y, b2w, b2h, tx, ty, tw, th);
    bool pick1 = i1 > i2;
    float iou = pick1 ? i1 : i2;
    float sc  = pick1 ? b1c : b2c;
    float sx  = pick1 ? b1x : b2x;
    float sy  = pick1 ? b1y : b2y;
    float sw  = pick1 ? b1w : b2w;
    float sh  = pick1 ? b1h : b2h;
    float uc  = pick1 ? b2c : b1c;

    float dx = sx - tx, dy = sy - ty;
    // sign(w)*sqrt(|w|): copysign matches jnp.sign semantics for finite inputs.
    float dw = copysignf(sqrtf(fabsf(sw)), sw) - sqrtf(tw);
    float dh = copysignf(sqrtf(fabsf(sh)), sh) - sqrtf(th);
    float l_coord = dx * dx + dy * dy + dw * dw + dh * dh;

    float doj = sc - iou;
    float d0 = p[10] - tg[5], d1 = p[11] - tg[6], d2 = p[12] - tg[7];
    float l_cls = d0 * d0 + d1 * d1 + d2 * d2;
    float l_noobj = m * uc * uc + (1.0f - m) * (b1c * b1c + b2c * b2c);

    return m * (L_COORD * l_coord + doj * doj + l_cls) + L_NOOBJ * l_noobj;
}

__global__ __launch_bounds__(256) void yolo_main(const float* __restrict__ pred,
                                                 const float* __restrict__ tgt,
                                                 float* __restrict__ partial,
                                                 long long ntiles, long long ncells) {
    __shared__ float sp[4][WTILE_F];   // private 3328B slab per wave
    __shared__ float wsum[4];

    const int t    = threadIdx.x;
    const int lane = t & 63;
    const int wave = t >> 6;
    const long long gw0    = (long long)blockIdx.x * 4 + wave;
    const long long nwaves = (long long)gridDim.x * 4;

    float acc = 0.0f;

    for (long long tile = gw0; tile < ntiles; tile += nwaves) {
        const long long cbase = tile * WTILE;

        if (cbase + WTILE <= ncells) {
            // --- stage 64 cells x 13 floats = 208 float4 of pred, coalesced ---
            const float* gp = pred + cbase * (long long)PRED_C;
#pragma unroll
            for (int r = 0; r < 3; ++r) {
                __builtin_amdgcn_global_load_lds(
                    (gp1_t)(gp + (size_t)(r * 64 + lane) * 4),
                    (lp3_t)(&sp[wave][r * 256]),
                    16, 0, 0);
            }
            if (lane < 16) {   // 208 = 3*64 + 16: exec-masked tail round
                __builtin_amdgcn_global_load_lds(
                    (gp1_t)(gp + (size_t)(192 + lane) * 4),
                    (lp3_t)(&sp[wave][768]),
                    16, 0, 0);
            }
            // --- my cell's target straight to regs (lane-stride 32B) ---
            const float4* t4 = (const float4*)(tgt + (cbase + lane) * (long long)TGT_C);
            float4 T0 = t4[0];
            float4 T1 = t4[1];

            // per-wave wait for our own staging loads (vmcnt(0), lgkm/exp no-wait);
            // defensive in case the compiler misses the LDS-alias dependency.
            __builtin_amdgcn_s_waitcnt(0x0F70);

            float tg[TGT_C] = {T0.x, T0.y, T0.z, T0.w, T1.x, T1.y, T1.z, T1.w};
            float pb[PRED_C];
#pragma unroll
            for (int i = 0; i < PRED_C; ++i)        // stride-13 dwords: 2-way = free
                pb[i] = sp[wave][lane * PRED_C + i];

            acc += cell_loss(pb, tg);
        } else {
            // tail tile (not hit at bench shape): guarded scalar path
            long long cell = cbase + lane;
            if (cell < ncells) {
                float pb[PRED_C], tb[TGT_C];
                for (int i = 0; i < PRED_C; ++i) pb[i] = pred[cell * PRED_C + i];
                for (int i = 0; i < TGT_C; ++i)  tb[i] = tgt[cell * TGT_C + i];
                acc += cell_loss(pb, tb);
            }
        }
    }

    // wave64 shuffle reduction -> one partial per block (deterministic)
#pragma unroll
    for (int off = 32; off > 0; off >>= 1)
        acc += __shfl_down(acc, off, 64);
    if (lane == 0) wsum[wave] = acc;
    __syncthreads();
    if (t == 0) partial[blockIdx.x] = (wsum[0] + wsum[1]) + (wsum[2] + wsum[3]);
}

__global__ __launch_bounds__(256) void yolo_reduce(const float* __restrict__ partial,
                                                   float* __restrict__ out,
                                                   int nblocks, float inv_batch) {
    __shared__ float wsum[4];
    int t = threadIdx.x;
    float v = 0.0f;
    for (int i = t; i < nblocks; i += 256) v += partial[i];
#pragma unroll
    for (int off = 32; off > 0; off >>= 1)
        v += __shfl_down(v, off, 64);
    if ((t & 63) == 0) wsum[t >> 6] = v;
    __syncthreads();
    if (t == 0) out[0] = ((wsum[0] + wsum[1]) + (wsum[2] + wsum[3])) * inv_batch;
}

extern "C" void kernel_launch(void* const* d_in, const int* in_sizes, int n_in,
                              void* d_out, int out_size, void* d_ws, size_t ws_size,
                              hipStream_t stream) {
    const float* pred = (const float*)d_in[0];
    const float* tgt  = (const float*)d_in[1];
    float* out = (float*)d_out;
    float* partial = (float*)d_ws;                       // NBLOCKS floats

    long long ncells = (long long)in_sizes[1] / TGT_C;   // batch*S*S = 1,605,632
    long long batch  = ncells / 49;                      // S=7
    float inv_batch  = 1.0f / (float)batch;
    long long ntiles = (ncells + WTILE - 1) / WTILE;     // 25,088

    yolo_main<<<NBLOCKS, 256, 0, stream>>>(pred, tgt, partial, ntiles, ncells);
    yolo_reduce<<<1, 256, 0, stream>>>(partial, out, NBLOCKS, inv_batch);
}